// Round 1
// 1382.329 us; speedup vs baseline: 1.2156x; 1.2156x over previous
//
#include <hip/hip_runtime.h>
#include <math.h>

// ExaoneMoe: router(fp32) + grouped-topk + routed experts (bf16 MFMA) + shared expert.
// R1: latency-bound fix — reg-prefetch 2-phase pipeline (loads for tile k+1 issued
// under MFMA of tile k), XOR-swizzled conflict-free LDS, 2m x 2n wave tiling
// (accums 128->64 regs so the prefetch fits at 2 blocks/CU), XCD-chunked block
// remap for L2 locality of per-expert weight/activation panels.

#define TOK 2048
#define HD 2048
#define NE 64
#define FD 768
#define TKK 6
#define CAPE 384
#define NG 8
#define KGG 4

typedef float f32x4 __attribute__((ext_vector_type(4)));
typedef short s16x8 __attribute__((ext_vector_type(8)));
typedef short s16x4 __attribute__((ext_vector_type(4)));

__device__ __forceinline__ short f2bf(float f){
  unsigned u = __float_as_uint(f);
  u += 0x7FFFu + ((u >> 16) & 1u);   // RNE
  return (short)(u >> 16);
}

// XOR-swizzled LDS offset (in shorts) for a row-major [r][64]-short tile.
// 16B chunk c of row r is stored at chunk (c ^ r ^ (r>>2)) & 7.
// Gives <=2-way bank aliasing (free, m136) for both our b128 reads
// (16 lanes = 16 consecutive rows, fixed chunk) and our staging writes.
__device__ __forceinline__ int lsw(int r, int c){
  return r * 64 + (((c ^ r ^ (r >> 2)) & 7) << 3);
}

// XCD-chunked remap: dispatch round-robins linear block id across 8 XCDs, so
// giving XCD x the contiguous work range [x*nwg/8, (x+1)*nwg/8) keeps all
// blocks of one expert on one XCD -> weight m-pair re-reads and A-panel
// re-reads hit that XCD's L2. Requires nwg % 8 == 0 (all our grids comply).
__device__ __forceinline__ void xcd_decode(int& bx, int& by, int& bz){
  const int nx = gridDim.x, ny = gridDim.y;
  const int nwg = nx * ny * gridDim.z;
  const int lid = blockIdx.x + nx * (blockIdx.y + ny * blockIdx.z);
  const int wid = (nwg & 7) ? lid : ((lid & 7) * (nwg >> 3) + (lid >> 3));
  bx = wid % nx; const int r = wid / nx; by = r % ny; bz = r / ny;
}

// ---------------- x fp32 -> bf16 ----------------
__global__ void k_convert(const float* __restrict__ x, short* __restrict__ xbf){
  int i = blockIdx.x * 256 + threadIdx.x;
  f32x4 v = ((const f32x4*)x)[i];
  s16x4 o = { f2bf(v[0]), f2bf(v[1]), f2bf(v[2]), f2bf(v[3]) };
  ((s16x4*)xbf)[i] = o;
}

// ---------------- router logits (fp32, selection-critical) ----------------
__global__ void k_router(const float* __restrict__ x, const float* __restrict__ gw,
                         float* __restrict__ logits){
  const int t = blockIdx.x * 4 + (threadIdx.x >> 6);
  const int e = threadIdx.x & 63;
  const float* xr = x + (size_t)t * HD;
  float acc = 0.f;
  for (int h = 0; h < HD; h += 4){
    f32x4 xv = *(const f32x4*)(xr + h);
    acc = fmaf(xv[0], gw[(h + 0) * NE + e], acc);
    acc = fmaf(xv[1], gw[(h + 1) * NE + e], acc);
    acc = fmaf(xv[2], gw[(h + 2) * NE + e], acc);
    acc = fmaf(xv[3], gw[(h + 3) * NE + e], acc);
  }
  logits[t * NE + e] = acc;
}

// ---------------- grouped topk + binning ----------------
__global__ void k_topk(const float* __restrict__ logits, const float* __restrict__ bias,
                       int* __restrict__ cnt, int* __restrict__ tokl, float* __restrict__ wl){
  const int t = blockIdx.x * 256 + threadIdx.x;
  float sc[NE], sb[NE];
  for (int e = 0; e < NE; ++e){
    float l = logits[t * NE + e];
    float s = 1.f / (1.f + expf(-l));
    sc[e] = s; sb[e] = s + bias[e];
  }
  float gs[NG];
  for (int g = 0; g < NG; ++g){
    float m1 = -1e30f, m2 = -1e30f;
    for (int q = 0; q < 8; ++q){
      float v = sb[g * 8 + q];
      if (v > m1){ m2 = m1; m1 = v; } else if (v > m2){ m2 = v; }
    }
    gs[g] = m1 + m2;
  }
  unsigned gm = 0; unsigned long long allow = 0;
  for (int r = 0; r < KGG; ++r){
    float bb = -1e30f; int bg = 0;
    for (int g = 0; g < NG; ++g)
      if (!((gm >> g) & 1u) && gs[g] > bb){ bb = gs[g]; bg = g; }   // strict > = JAX tie-break
    gm |= 1u << bg; allow |= 0xFFull << (bg * 8);
  }
  unsigned long long used = 0; int ids[TKK]; float wv[TKK]; float wsum = 0.f;
  for (int r = 0; r < TKK; ++r){
    float bb = -1e30f; int bi = 0;
    for (int e = 0; e < NE; ++e)
      if (((allow >> e) & 1ull) && !((used >> e) & 1ull) && sb[e] > bb){ bb = sb[e]; bi = e; }
    used |= 1ull << bi; ids[r] = bi;
    float w = sc[bi]; wv[r] = w; wsum += w;     // weights from UNBIASED scores
  }
  const float scl = 2.5f / wsum;
  for (int r = 0; r < TKK; ++r){
    int e = ids[r];
    int slot = atomicAdd(cnt + e, 1);
    if (slot < CAPE){ tokl[e * CAPE + slot] = t; wl[e * CAPE + slot] = wv[r] * scl; }
  }
}

// ---------------- dual (gate||up) GEMM + silu-mul -> bf16 h ----------------
// M_tile=128, N_tile=64, BK=64; 4 waves as 2m x 2n, per-wave 64x32 output.
// Reg-prefetch pipeline: loads for k+1 issued right after the staging barrier,
// converted after the MFMAs, ds_written at the top of the next iter.
template<bool GATHER>
__global__ __launch_bounds__(256, 2) void k_dual(
    const short* __restrict__ xbf,
    const float* __restrict__ Wg, const float* __restrict__ Wu,
    short* __restrict__ hout,
    const int* __restrict__ cnt, const int* __restrict__ tokl)
{
  __shared__ __align__(16) short As[128 * 64];
  __shared__ __align__(16) short Bgs[64 * 64];
  __shared__ __align__(16) short Bus[64 * 64];
  int bx, by, bz; xcd_decode(bx, by, bz);
  const int n0 = bx * 64;
  const int m0 = by * 128;
  const int e  = GATHER ? bz : 0;
  const int cntc = GATHER ? min(cnt[e], CAPE) : TOK;
  if (m0 >= cntc) return;
  const size_t wb = (size_t)e * HD * FD;
  const float* wg = Wg + wb + n0;
  const float* wu = Wu + wb + n0;

  const int tid = threadIdx.x;
  const int a_r = tid >> 3, a_c = tid & 7;
  const short* arow[4];
#pragma unroll
  for (int p = 0; p < 4; ++p){
    const int gr = m0 + p * 32 + a_r;
    const short* s = nullptr;
    if (gr < cntc){
      const int row = GATHER ? tokl[e * CAPE + gr] : gr;
      s = xbf + (size_t)row * HD;
    }
    arow[p] = s;
  }
  const int b_kg = tid >> 4, b_ng = tid & 15;
  const int lane = tid & 63, wv = tid >> 6;
  const int wm = wv >> 1, wn = wv & 1;
  const int lm = lane & 15, quad = lane >> 4;

  f32x4 ag[4][2], au[4][2];
#pragma unroll
  for (int i = 0; i < 4; ++i)
#pragma unroll
    for (int j = 0; j < 2; ++j){ ag[i][j] = {0.f,0.f,0.f,0.f}; au[i][j] = {0.f,0.f,0.f,0.f}; }

  s16x8 apf[4];          // prefetched A tile (bf16, 16 VGPR)
  f32x4 gf[4], uf[4];    // prefetched B tiles (fp32, transient 32 VGPR)
  s16x4 gc[4], uc[4];    // converted B tiles (bf16, 16 VGPR)
  const s16x8 zz = {0,0,0,0,0,0,0,0};

  auto LOADA = [&](int k0){
#pragma unroll
    for (int p = 0; p < 4; ++p)
      apf[p] = arow[p] ? *(const s16x8*)(arow[p] + k0 + a_c * 8) : zz;
  };
  auto LOADB = [&](int k0){
    const float* s1 = wg + (size_t)(k0 + b_kg * 4) * FD + b_ng * 4;
    gf[0] = *(const f32x4*)(s1);
    gf[1] = *(const f32x4*)(s1 + FD);
    gf[2] = *(const f32x4*)(s1 + 2 * FD);
    gf[3] = *(const f32x4*)(s1 + 3 * FD);
    const float* s2 = wu + (size_t)(k0 + b_kg * 4) * FD + b_ng * 4;
    uf[0] = *(const f32x4*)(s2);
    uf[1] = *(const f32x4*)(s2 + FD);
    uf[2] = *(const f32x4*)(s2 + 2 * FD);
    uf[3] = *(const f32x4*)(s2 + 3 * FD);
  };
  auto CONVB = [&](){
#pragma unroll
    for (int c = 0; c < 4; ++c){
      s16x4 g4 = { f2bf(gf[0][c]), f2bf(gf[1][c]), f2bf(gf[2][c]), f2bf(gf[3][c]) };
      s16x4 u4 = { f2bf(uf[0][c]), f2bf(uf[1][c]), f2bf(uf[2][c]), f2bf(uf[3][c]) };
      gc[c] = g4; uc[c] = u4;
    }
  };

  LOADA(0); LOADB(0); CONVB();

  for (int k0 = 0; k0 < HD; k0 += 64){
    __syncthreads();                       // all waves done reading LDS (prev tile)
#pragma unroll
    for (int p = 0; p < 4; ++p)
      *(s16x8*)&As[lsw(p * 32 + a_r, a_c)] = apf[p];
#pragma unroll
    for (int c = 0; c < 4; ++c){
      const int n = b_ng * 4 + c;
      const int off = n * 64 + ((((b_kg >> 1) ^ n ^ (n >> 2)) & 7) << 3) + ((b_kg & 1) << 2);
      *(s16x4*)&Bgs[off] = gc[c];
      *(s16x4*)&Bus[off] = uc[c];
    }
    __syncthreads();                       // LDS tile k ready
    const bool more = (k0 + 64) < HD;
    if (more){ LOADA(k0 + 64); LOADB(k0 + 64); }   // fly under the MFMAs below
#pragma unroll
    for (int s = 0; s < 2; ++s){
      const int cc = s * 4 + quad;
      s16x8 af[4], bgr[2], bur[2];
#pragma unroll
      for (int i = 0; i < 4; ++i)
        af[i] = *(const s16x8*)&As[lsw(wm * 64 + i * 16 + lm, cc)];
#pragma unroll
      for (int j = 0; j < 2; ++j){
        bgr[j] = *(const s16x8*)&Bgs[lsw(wn * 32 + j * 16 + lm, cc)];
        bur[j] = *(const s16x8*)&Bus[lsw(wn * 32 + j * 16 + lm, cc)];
      }
#pragma unroll
      for (int i = 0; i < 4; ++i)
#pragma unroll
        for (int j = 0; j < 2; ++j){
          ag[i][j] = __builtin_amdgcn_mfma_f32_16x16x32_bf16(af[i], bgr[j], ag[i][j], 0, 0, 0);
          au[i][j] = __builtin_amdgcn_mfma_f32_16x16x32_bf16(af[i], bur[j], au[i][j], 0, 0, 0);
        }
    }
    if (more) CONVB();                     // vmcnt waits land here, after the MFMAs
  }

  const size_t obase = GATHER ? (size_t)e * CAPE : 0;
#pragma unroll
  for (int i = 0; i < 4; ++i){
#pragma unroll
    for (int r = 0; r < 4; ++r){
      const int grow = m0 + wm * 64 + i * 16 + quad * 4 + r;
      if (grow < cntc){
        short* orow = hout + (obase + grow) * FD + n0 + wn * 32;
#pragma unroll
        for (int j = 0; j < 2; ++j){
          const float g = ag[i][j][r], u = au[i][j][r];
          orow[j * 16 + lm] = f2bf(g * u / (1.f + __expf(-g)));   // silu(g)*u
        }
      }
    }
  }
}

// ---------------- down GEMM; SCATTER: weighted atomicAdd, else plain store ----------------
// Same pipeline; single B matrix -> ~120 regs, 24KB LDS -> 3-4 blocks/CU.
template<bool SCATTER>
__global__ __launch_bounds__(256, 3) void k_down(
    const short* __restrict__ hsrc,
    const float* __restrict__ Wd,
    float* __restrict__ out,
    const int* __restrict__ cnt, const int* __restrict__ tokl, const float* __restrict__ wl)
{
  __shared__ __align__(16) short As[128 * 64];
  __shared__ __align__(16) short Bs[64 * 64];
  int bx, by, bz; xcd_decode(bx, by, bz);
  const int n0 = bx * 64;
  const int m0 = by * 128;
  const int e  = SCATTER ? bz : 0;
  const int cntc = SCATTER ? min(cnt[e], CAPE) : TOK;
  if (m0 >= cntc) return;
  const short* abase = hsrc + (size_t)e * CAPE * FD;
  const float* wd = Wd + (size_t)e * FD * HD + n0;

  const int tid = threadIdx.x;
  const int a_r = tid >> 3, a_c = tid & 7;
  const short* arow[4];
#pragma unroll
  for (int p = 0; p < 4; ++p){
    const int gr = m0 + p * 32 + a_r;
    arow[p] = (gr < cntc) ? (abase + (size_t)gr * FD) : nullptr;
  }
  const int b_kg = tid >> 4, b_ng = tid & 15;
  const int lane = tid & 63, wv = tid >> 6;
  const int wm = wv >> 1, wn = wv & 1;
  const int lm = lane & 15, quad = lane >> 4;

  f32x4 ac[4][2];
#pragma unroll
  for (int i = 0; i < 4; ++i)
#pragma unroll
    for (int j = 0; j < 2; ++j) ac[i][j] = {0.f,0.f,0.f,0.f};

  s16x8 apf[4];
  f32x4 df[4];
  s16x4 dc[4];
  const s16x8 zz = {0,0,0,0,0,0,0,0};

  auto LOADA = [&](int k0){
#pragma unroll
    for (int p = 0; p < 4; ++p)
      apf[p] = arow[p] ? *(const s16x8*)(arow[p] + k0 + a_c * 8) : zz;
  };
  auto LOADB = [&](int k0){
    const float* s1 = wd + (size_t)(k0 + b_kg * 4) * HD + b_ng * 4;
    df[0] = *(const f32x4*)(s1);
    df[1] = *(const f32x4*)(s1 + HD);
    df[2] = *(const f32x4*)(s1 + 2 * HD);
    df[3] = *(const f32x4*)(s1 + 3 * HD);
  };
  auto CONVB = [&](){
#pragma unroll
    for (int c = 0; c < 4; ++c){
      s16x4 d4 = { f2bf(df[0][c]), f2bf(df[1][c]), f2bf(df[2][c]), f2bf(df[3][c]) };
      dc[c] = d4;
    }
  };

  LOADA(0); LOADB(0); CONVB();

  for (int k0 = 0; k0 < FD; k0 += 64){
    __syncthreads();
#pragma unroll
    for (int p = 0; p < 4; ++p)
      *(s16x8*)&As[lsw(p * 32 + a_r, a_c)] = apf[p];
#pragma unroll
    for (int c = 0; c < 4; ++c){
      const int n = b_ng * 4 + c;
      const int off = n * 64 + ((((b_kg >> 1) ^ n ^ (n >> 2)) & 7) << 3) + ((b_kg & 1) << 2);
      *(s16x4*)&Bs[off] = dc[c];
    }
    __syncthreads();
    const bool more = (k0 + 64) < FD;
    if (more){ LOADA(k0 + 64); LOADB(k0 + 64); }
#pragma unroll
    for (int s = 0; s < 2; ++s){
      const int cc = s * 4 + quad;
      s16x8 af[4], bfr[2];
#pragma unroll
      for (int i = 0; i < 4; ++i)
        af[i] = *(const s16x8*)&As[lsw(wm * 64 + i * 16 + lm, cc)];
#pragma unroll
      for (int j = 0; j < 2; ++j)
        bfr[j] = *(const s16x8*)&Bs[lsw(wn * 32 + j * 16 + lm, cc)];
#pragma unroll
      for (int i = 0; i < 4; ++i)
#pragma unroll
        for (int j = 0; j < 2; ++j)
          ac[i][j] = __builtin_amdgcn_mfma_f32_16x16x32_bf16(af[i], bfr[j], ac[i][j], 0, 0, 0);
    }
    if (more) CONVB();
  }

#pragma unroll
  for (int i = 0; i < 4; ++i){
#pragma unroll
    for (int r = 0; r < 4; ++r){
      const int grow = m0 + wm * 64 + i * 16 + quad * 4 + r;
      if (grow < cntc){
        if (SCATTER){
          const int t = tokl[e * CAPE + grow];
          const float w = wl[e * CAPE + grow];
          float* orow = out + (size_t)t * HD + n0 + wn * 32;
#pragma unroll
          for (int j = 0; j < 2; ++j)
            atomicAdd(orow + j * 16 + lm, w * ac[i][j][r]);
        } else {
          float* orow = out + (size_t)grow * HD + n0 + wn * 32;
#pragma unroll
          for (int j = 0; j < 2; ++j)
            orow[j * 16 + lm] = ac[i][j][r];
        }
      }
    }
  }
}

extern "C" void kernel_launch(void* const* d_in, const int* in_sizes, int n_in,
                              void* d_out, int out_size, void* d_ws, size_t ws_size,
                              hipStream_t stream){
  const float* x    = (const float*)d_in[0];
  const float* gw   = (const float*)d_in[1];
  const float* bias = (const float*)d_in[2];
  const float* wgat = (const float*)d_in[3];
  const float* wup  = (const float*)d_in[4];
  const float* wdn  = (const float*)d_in[5];
  const float* wsg  = (const float*)d_in[6];
  const float* wsu  = (const float*)d_in[7];
  const float* wsd  = (const float*)d_in[8];
  float* out = (float*)d_out;
  char* ws = (char*)d_ws;

  // ws layout (all 16B aligned), total 50,004,224 B
  short* xbf    = (short*)(ws);                      //  8,388,608
  short* hbuf   = (short*)(ws + 8388608);            // 37,748,736
  short* hs     = (short*)(ws + 46137344);           //  3,145,728
  float* logits = (float*)(ws + 49283072);           //    524,288
  int*   tokl   = (int*)  (ws + 49807360);           //     98,304
  float* wl     = (float*)(ws + 49905664);           //     98,304
  int*   cnt    = (int*)  (ws + 50003968);           //        256
  if (ws_size < 50004224) return;                    // clean wrong-answer instead of OOB

  hipMemsetAsync(cnt, 0, NE * sizeof(int), stream);
  k_convert<<<dim3(TOK * HD / 1024), 256, 0, stream>>>(x, xbf);
  k_router<<<dim3(TOK / 4), 256, 0, stream>>>(x, gw, logits);
  k_topk<<<dim3(TOK / 256), 256, 0, stream>>>(logits, bias, cnt, tokl, wl);
  // shared expert: initializes d_out fully (plain stores)
  k_dual<false><<<dim3(FD / 64, TOK / 128, 1), 256, 0, stream>>>(xbf, wsg, wsu, hs, nullptr, nullptr);
  k_down<false><<<dim3(HD / 64, TOK / 128, 1), 256, 0, stream>>>(hs, wsd, out, nullptr, nullptr, nullptr);
  // routed experts: h = silu(xWg)*xWu, then weighted atomic scatter of hWd
  k_dual<true><<<dim3(FD / 64, CAPE / 128, NE), 256, 0, stream>>>(xbf, wgat, wup, hbuf, cnt, tokl);
  k_down<true><<<dim3(HD / 64, CAPE / 128, NE), 256, 0, stream>>>(hbuf, wdn, out, cnt, tokl, wl);
}